// Round 2
// baseline (555.998 us; speedup 1.0000x reference)
//
#include <hip/hip_runtime.h>
#include <stdint.h>

#define Bn 16
#define C 64
#define H 256
#define W 256
#define HW (H * W)          // 65536
#define HW4 (HW / 4)        // 16384
#define NHW (Bn * HW)       // 1048576

// ---------------------------------------------------------------------------
// Kernel 1: weight prep. One wave per output channel o.
// wbits[o*9 + tap] bit c = (w[o][c][tap] > 0)
// params[o] = { scale, pr_bias0, prelu_a, pr_bias1 }
// ---------------------------------------------------------------------------
__global__ void prep_weights(const float* __restrict__ w,
                             const float* __restrict__ pb0,
                             const float* __restrict__ aw,
                             const float* __restrict__ pb1,
                             uint64_t* __restrict__ wbits,
                             float4* __restrict__ params) {
    int o = blockIdx.x;     // 64 blocks
    int c = threadIdx.x;    // 64 threads = 1 wave
    const float* wp = w + ((size_t)o * C + c) * 9;
    float asum = 0.f;
#pragma unroll
    for (int tap = 0; tap < 9; ++tap) {
        float v = wp[tap];
        asum += fabsf(v);
        uint64_t m = __ballot(v > 0.f);   // bit c = sign of channel c
        if (c == 0) wbits[o * 9 + tap] = m;
    }
#pragma unroll
    for (int off = 32; off > 0; off >>= 1)
        asum += __shfl_down(asum, off);
    if (c == 0)
        params[o] = make_float4(asum * (1.f / 576.f), pb0[o], aw[o], pb1[o]);
}

// ---------------------------------------------------------------------------
// Kernel 2: pack z = sign(x + bias), 4 pixels (consecutive w) per thread.
// float4 loads of x; two 16B stores of the 4 packed uint64 words.
// ---------------------------------------------------------------------------
__global__ __launch_bounds__(256) void pack_z4(const float* __restrict__ x,
                                               const float* __restrict__ bias,
                                               uint64_t* __restrict__ zbits) {
    int p = blockIdx.x * 256 + threadIdx.x;   // NHW/4 threads total
    int n = p >> 14;                          // / HW4
    int hw4 = (p & (HW4 - 1)) << 2;
    const float* xp = x + ((size_t)n << 22) + hw4;
    uint64_t b0 = 0, b1 = 0, b2 = 0, b3 = 0;
#pragma unroll 8
    for (int c = 0; c < C; ++c) {
        float4 v = *(const float4*)(xp + ((size_t)c << 16));
        float bc = bias[c];                   // uniform -> s_load
        b0 |= (uint64_t)(v.x + bc > 0.f) << c;
        b1 |= (uint64_t)(v.y + bc > 0.f) << c;
        b2 |= (uint64_t)(v.z + bc > 0.f) << c;
        b3 |= (uint64_t)(v.w + bc > 0.f) << c;
    }
    uint64_t* zp = zbits + ((size_t)n << 16) + hw4;
    uint4 lo = make_uint4((uint32_t)b0, (uint32_t)(b0 >> 32),
                          (uint32_t)b1, (uint32_t)(b1 >> 32));
    uint4 hi = make_uint4((uint32_t)b2, (uint32_t)(b2 >> 32),
                          (uint32_t)b3, (uint32_t)(b3 >> 32));
    *(uint4*)zp = lo;
    *((uint4*)zp + 1) = hi;
}

// ---------------------------------------------------------------------------
// Kernel 3: binary conv + RPReLU + residual. Thread = 4 pixels (along w),
// all 64 output channels. Weights + params are wave-uniform -> scalar loads.
//   dot_j[o] = base_j - 2 * sum_{valid taps} popc(w ^ z)
// ---------------------------------------------------------------------------
__global__ __launch_bounds__(256) void bconv4(const uint64_t* __restrict__ zbits,
                                              const uint64_t* __restrict__ wbits,
                                              const float4* __restrict__ params,
                                              const float* __restrict__ x,
                                              float* __restrict__ out) {
    int p = blockIdx.x * 256 + threadIdx.x;   // NHW/4 threads total
    int n = p >> 14;
    int hw4 = (p & (HW4 - 1)) << 2;
    int h = hw4 >> 8;
    int w0 = hw4 & (W - 1);                   // multiple of 4

    const uint64_t* zimg = zbits + ((size_t)n << 16);

    // 3x6 sliding window of packed z words: rows h-1..h+1, cols w0-1..w0+4.
    // Invalid taps are masked out of the popcount sum (conv zero-padding).
    uint64_t zwin[3][6];
    int rm[3], rmc0[3], rmc5[3];
    int cm0 = (w0 > 0) ? -1 : 0;              // col w0-1 valid
    int cm5 = (w0 < W - 4) ? -1 : 0;          // col w0+4 valid
    int c0 = (w0 > 0) ? w0 - 1 : 0;           // clamp to avoid OOB-before-buffer
#pragma unroll
    for (int r = 0; r < 3; ++r) {
        int hh = h - 1 + r;
        bool rv = (unsigned)hh < (unsigned)H;
        rm[r] = rv ? -1 : 0;
        rmc0[r] = rm[r] & cm0;
        rmc5[r] = rm[r] & cm5;
        int hc = rv ? hh : h;                 // clamped row (value masked anyway)
        const uint64_t* zr = zimg + hc * W;
        zwin[r][0] = zr[c0];
        zwin[r][1] = zr[w0];
        zwin[r][2] = zr[w0 + 1];
        zwin[r][3] = zr[w0 + 2];
        zwin[r][4] = zr[w0 + 3];
        zwin[r][5] = zr[w0 + 4];   // at w0=252 reads 1 word past row: masked, in-bounds of ws
    }

    // base_j = 64 * (# valid taps for pixel j)
    int base[4];
#pragma unroll
    for (int j = 0; j < 4; ++j) {
        int nv = 0;
#pragma unroll
        for (int r = 0; r < 3; ++r)
#pragma unroll
            for (int cc = 0; cc < 3; ++cc) {
                int k = j + cc;
                int mk = (k == 0) ? rmc0[r] : (k == 5) ? rmc5[r] : rm[r];
                nv += mk & 1;
            }
        base[j] = nv << 6;
    }

    const float* xbase = x + ((size_t)n << 22) + hw4;
    float* obase = out + ((size_t)n << 22) + hw4;

    for (int o = 0; o < C; ++o) {
        const uint64_t* wp = wbits + o * 9;   // uniform index -> s_load
        uint64_t wv[9];
#pragma unroll
        for (int t9 = 0; t9 < 9; ++t9) wv[t9] = wp[t9];

        int s0 = 0, s1 = 0, s2 = 0, s3 = 0;
#pragma unroll
        for (int r = 0; r < 3; ++r) {
#pragma unroll
            for (int cc = 0; cc < 3; ++cc) {
                uint64_t wt = wv[r * 3 + cc];
                {   // j = 0, k = cc
                    int mk = (cc == 0) ? rmc0[r] : rm[r];
                    s0 += mk & (int)__popcll(wt ^ zwin[r][cc]);
                }
                {   // j = 1
                    s1 += rm[r] & (int)__popcll(wt ^ zwin[r][1 + cc]);
                }
                {   // j = 2
                    s2 += rm[r] & (int)__popcll(wt ^ zwin[r][2 + cc]);
                }
                {   // j = 3, k = 3+cc
                    int mk = (cc == 2) ? rmc5[r] : rm[r];
                    s3 += mk & (int)__popcll(wt ^ zwin[r][3 + cc]);
                }
            }
        }

        float4 pr = params[o];                        // uniform -> s_load_dwordx4
        float4 xi = *(const float4*)(xbase + ((size_t)o << 16));

        float y0 = pr.x * (float)(base[0] - 2 * s0) + pr.y;
        float y1 = pr.x * (float)(base[1] - 2 * s1) + pr.y;
        float y2 = pr.x * (float)(base[2] - 2 * s2) + pr.y;
        float y3 = pr.x * (float)(base[3] - 2 * s3) + pr.y;
        y0 = (y0 > 0.f ? y0 : pr.z * y0) + pr.w + xi.x;
        y1 = (y1 > 0.f ? y1 : pr.z * y1) + pr.w + xi.y;
        y2 = (y2 > 0.f ? y2 : pr.z * y2) + pr.w + xi.z;
        y3 = (y3 > 0.f ? y3 : pr.z * y3) + pr.w + xi.w;

        *(float4*)(obase + ((size_t)o << 16)) = make_float4(y0, y1, y2, y3);
    }
}

// ---------------------------------------------------------------------------
extern "C" void kernel_launch(void* const* d_in, const int* in_sizes, int n_in,
                              void* d_out, int out_size, void* d_ws, size_t ws_size,
                              hipStream_t stream) {
    const float* x           = (const float*)d_in[0];
    const float* move0_bias  = (const float*)d_in[1];
    const float* conv_weight = (const float*)d_in[2];
    const float* prelu_w     = (const float*)d_in[3];
    const float* pr_bias0    = (const float*)d_in[4];
    const float* pr_bias1    = (const float*)d_in[5];
    float* out = (float*)d_out;

    uint8_t* ws = (uint8_t*)d_ws;
    uint64_t* zbits = (uint64_t*)ws;                                   // 8 MB
    uint64_t* wbits = (uint64_t*)(ws + (size_t)NHW * 8);               // 4608 B
    float4* params  = (float4*)(ws + (size_t)NHW * 8 + 640 * 8);       // 1 KB

    prep_weights<<<64, 64, 0, stream>>>(conv_weight, pr_bias0, prelu_w,
                                        pr_bias1, wbits, params);
    pack_z4<<<NHW / 1024, 256, 0, stream>>>(x, move0_bias, zbits);
    bconv4<<<NHW / 1024, 256, 0, stream>>>(zbits, wbits, params, x, out);
}